// Round 8
// baseline (694.875 us; speedup 1.0000x reference)
//
#include <hip/hip_runtime.h>
#include <math.h>

#define NB   8
#define TT   400
#define HH   128
#define CC   96
#define DD   4096
#define THRV (1.0f - 1e-5f)
#define XR   40      // f16 row pad: 80 B rows (5*16B -> b128-aligned, clean bank walk)
#define HEPS 4e-6f   // convergence tolerance (same class-proven margin as before)
#define S10  1024.0f            // lo-split scale (keeps lo out of f16 subnormals)
#define IS10 0.0009765625f      // 2^-10
#define IS20 9.5367431640625e-07f  // 2^-20

typedef _Float16 f16x8 __attribute__((ext_vector_type(8)));
typedef float    f32x4 __attribute__((ext_vector_type(4)));
typedef float    f32x2 __attribute__((ext_vector_type(2)));
typedef int      i32x4 __attribute__((ext_vector_type(4)));
typedef unsigned long long ull;

__device__ __forceinline__ float rcp_fast(float x) {
#if __has_builtin(__builtin_amdgcn_rcpf)
    return __builtin_amdgcn_rcpf(x);
#else
    return 1.0f / x;
#endif
}
// v_exp_f32-based sigmoid/tanh: ~1e-7 err, far inside the proven 5e-5 margin.
__device__ __forceinline__ float sigm(float v)  { return rcp_fast(1.0f + __expf(-v)); }
__device__ __forceinline__ float ftanh(float x) { return 1.0f - 2.0f * rcp_fast(1.0f + __expf(2.0f * x)); }

__device__ __forceinline__ void split2(float4 u0, float4 u1, f16x8& hi, f16x8& lo) {
    float x[8] = {u0.x, u0.y, u0.z, u0.w, u1.x, u1.y, u1.z, u1.w};
    #pragma unroll
    for (int e = 0; e < 8; ++e) {
        _Float16 h = (_Float16)x[e];
        hi[e] = h;
        lo[e] = (_Float16)(x[e] - (float)h);
    }
}
// scaled variant: lo is stored *1024 so residuals stay in f16 normal range
__device__ __forceinline__ void split2s(float4 u0, float4 u1, f16x8& hi, f16x8& lo) {
    float x[8] = {u0.x, u0.y, u0.z, u0.w, u1.x, u1.y, u1.z, u1.w};
    #pragma unroll
    for (int e = 0; e < 8; ++e) {
        _Float16 h = (_Float16)x[e];
        hi[e] = h;
        lo[e] = (_Float16)((x[e] - (float)h) * S10);
    }
}
__device__ __forceinline__ void split1(float x, _Float16& hi, _Float16& lo) {
    hi = (_Float16)x;
    lo = (_Float16)(x - (float)hi);
}

// lane ^ 32 combine on the VALU pipe (keeps the LDS pipe free)
__device__ __forceinline__ float xsum32(float v) {
#if __has_builtin(__builtin_amdgcn_permlane32_swap)
    auto r = __builtin_amdgcn_permlane32_swap(__float_as_uint(v), __float_as_uint(v), false, false);
    return __uint_as_float(r[0]) + __uint_as_float(r[1]);
#else
    return v + __shfl_xor(v, 32, 64);
#endif
}

// Barrier WITHOUT the vmcnt(0) drain __syncthreads would emit: global stores
// (out[]) are fire-and-forget (nothing reads them), so only LDS ops need to
// complete before waves cross.
__device__ __forceinline__ void step_barrier() {
    __builtin_amdgcn_sched_barrier(0);
    asm volatile("s_waitcnt lgkmcnt(0)" ::: "memory");
    __builtin_amdgcn_s_barrier();
    asm volatile("" ::: "memory");
    __builtin_amdgcn_sched_barrier(0);
}

// LDS = 103 KB -> only ONE 16-wave block fits per CU regardless of VGPRs, i.e.
// 4 waves/EU. Declare that (2nd arg = min waves/EU) so the allocator gets the
// full 128-VGPR budget instead of pinning to 64 and spilling the i8-corr state
// to scratch every loop iteration (R7: FETCH_SIZE 42->99 MB = spill traffic).
__global__ __launch_bounds__(1024, 4)
void gru_title(const float* __restrict__ img,
               const float* __restrict__ l1w,
               const float* __restrict__ l1b,
               const float* __restrict__ wih,
               const float* __restrict__ whh,
               const float* __restrict__ bih,
               const float* __restrict__ bhh,
               const float* __restrict__ l2w,
               const float* __restrict__ l2b,
               float* __restrict__ out,
               float* __restrict__ lens)
{
    // M-packed A layout (proven in R4/R5): value (m,k,hi) at row 16*((k>>3)&3)+m,
    // lo at +8; f16 col 8*(k>>5)+(k&7). A-frag read = row=lane, col=8*kt.
    __shared__ alignas(16) _Float16 x2 [2][64][XR];   // h: hi rows 0-7, lo rows 8-15 per 16-group
    __shared__ alignas(16) _Float16 l2v[2][64][XR];   // leaky(h), same layout
    __shared__ alignas(16) char     x2i8[2][64][32];  // i8(h*127): rows (l&15)<8 data, rest 0
    __shared__ alignas(16) _Float16 bcS[2][6][4][4][16][8]; // chars weights hi(0)/lo(1), 48 KB
    __shared__ alignas(16) float    gEx[4096];        // gate exchange [m][i][g], XOR ((m&3)<<5)
    __shared__ alignas(16) float    scr[2048];        // chs[2][8][128]  UNION  xsP[2][8][128]
    __shared__ alignas(16) float    xs0[NB][HH];      // x0 (t=0 path)
    __shared__ int sh_st[4];                          // stable flags, 4-slot rotation

    const int tid  = threadIdx.x;
    const int b0   = blockIdx.x * NB;
    const int w    = tid >> 6;     // wave 0..15
    const int lane = tid & 63;
    const int lm   = lane & 15;
    const int lq   = lane >> 4;
    const int c8   = w & 7;        // i-chunk [16*c8, 16*c8+16)
    const int r8   = w >> 3;       // gate-pair half: 0 -> gates {r,z}, 1 -> {n_i,n_h}
    const int ic2  = 16 * c8 + lm;

    // ---- gate weights: this wave owns gates {2r8, 2r8+1} for chunk c8 ----
    // g=0: r (wih+whh fused, x==h for t>=1); g=1: z (fused); g=2: n_i; g=3: n_h
    // B hi in f16 frags; the ah*bl term is restored EXACTLY-ish via an i8 MFMA
    // correction (K=64, 2 MFMAs/gate): h->i8 (A, built in phase B), bl->i8 with
    // per-column scale (B, built here). Residual error ~1e-5 per gate pre-act.
    f16x8 bh[2][4];
    i32x4 bq[2][2];
    float gb[2], fq[2];
    #pragma unroll
    for (int gl = 0; gl < 2; ++gl) {
        const int g2 = 2 * r8 + gl;
        const float* r0;
        const float* r1 = nullptr;
        float bsum;
        if (g2 == 0)      { r0 = wih + (size_t)ic2 * HH;         r1 = whh + (size_t)ic2 * HH;         bsum = bih[ic2] + bhh[ic2]; }
        else if (g2 == 1) { r0 = wih + (size_t)(128 + ic2) * HH; r1 = whh + (size_t)(128 + ic2) * HH; bsum = bih[128 + ic2] + bhh[128 + ic2]; }
        else if (g2 == 2) { r0 = wih + (size_t)(256 + ic2) * HH;                                      bsum = bih[256 + ic2]; }
        else              { r0 = whh + (size_t)(256 + ic2) * HH;                                      bsum = bhh[256 + ic2]; }
        gb[gl] = bsum;
        float bl32[4][8];
        #pragma unroll
        for (int kt = 0; kt < 4; ++kt) {
            const int k0 = 32 * kt + 8 * lq;
            float4 u0 = *(const float4*)(r0 + k0);
            float4 u1 = *(const float4*)(r0 + k0 + 4);
            if (r1) {
                float4 e0 = *(const float4*)(r1 + k0);
                float4 e1 = *(const float4*)(r1 + k0 + 4);
                u0.x += e0.x; u0.y += e0.y; u0.z += e0.z; u0.w += e0.w;
                u1.x += e1.x; u1.y += e1.y; u1.z += e1.z; u1.w += e1.w;
            }
            float xv[8] = {u0.x, u0.y, u0.z, u0.w, u1.x, u1.y, u1.z, u1.w};
            f16x8 hiv;
            #pragma unroll
            for (int e = 0; e < 8; ++e) {
                _Float16 hh = (_Float16)xv[e];
                hiv[e] = hh;
                bl32[kt][e] = xv[e] - (float)hh;   // f32 residual (f16 would be subnormal)
            }
            bh[gl][kt] = hiv;
        }
        // per-column |bl| max across all K (this lane holds k = 32kt+8lq+e; the
        // 4 lanes sharing lm (lq=0..3) cover the column)
        float mx = 0.f;
        #pragma unroll
        for (int kt = 0; kt < 4; ++kt)
            #pragma unroll
            for (int e = 0; e < 8; ++e) mx = fmaxf(mx, fabsf(bl32[kt][e]));
        mx = fmaxf(mx, __shfl_xor(mx, 16, 64));
        mx = fmaxf(mx, __shfl_xor(mx, 32, 64));
        const float inv = (mx > 0.f) ? 127.0f / mx : 0.f;
        fq[gl] = mx * (1.0f / 16129.0f);   // dequant: (q_a q_b) * mx/(127*127)
        // quantize + pack own 8 bytes per kt (byte e = k 32kt+8lq+e, LSB-first)
        ull p[4];
        #pragma unroll
        for (int kt = 0; kt < 4; ++kt) {
            ull pv = 0;
            #pragma unroll
            for (int e = 0; e < 8; ++e) {
                int q = (int)rintf(bl32[kt][e] * inv);
                pv |= ((ull)((unsigned)q & 0xffu)) << (8 * e);
            }
            p[kt] = pv;
        }
        // gather into i8 B-frag order: frag kt' byte b <-> k = 64kt'+16lq+b.
        // src = lane (lm, (2lq+(b>=8))&3), p-index 2kt'+(lq>>1). Double-shuffle
        // (uniform indices) + select by lq&2.
        #pragma unroll
        for (int ktp = 0; ktp < 2; ++ktp) {
            ull s0a = __shfl(p[2 * ktp],     lm + 16 * ((2 * lq) & 3), 64);
            ull s0b = __shfl(p[2 * ktp + 1], lm + 16 * ((2 * lq) & 3), 64);
            ull lo8 = (lq & 2) ? s0b : s0a;
            ull s1a = __shfl(p[2 * ktp],     lm + 16 * ((2 * lq + 1) & 3), 64);
            ull s1b = __shfl(p[2 * ktp + 1], lm + 16 * ((2 * lq + 1) & 3), 64);
            ull hi8 = (lq & 2) ? s1b : s1a;
            i32x4 f;
            f[0] = (int)(unsigned)(lo8 & 0xffffffffu);
            f[1] = (int)(unsigned)(lo8 >> 32);
            f[2] = (int)(unsigned)(hi8 & 0xffffffffu);
            f[3] = (int)(unsigned)(hi8 >> 32);
            bq[gl][ktp] = f;
        }
    }

    // ---- chars: waves 1..6 own tile ct = w-1 (weights live in LDS; EXACT hi+lo) ----
    const int ct = (w >= 1 && w <= 6) ? (w - 1) : -1;
    float cb = 0.f;
    if (ct >= 0) cb = l2b[16 * ct + lm];

    // stage chars weights (hi + lo planes) in LDS; all threads help
    for (int idx = tid; idx < 6 * 4 * 4 * 16; idx += 1024) {
        int t_  = idx;
        int lm_ = t_ & 15; t_ >>= 4;
        int lq_ = t_ & 3;  t_ >>= 2;
        int kt_ = t_ & 3;  t_ >>= 2;
        int ct_ = t_;                       // 0..5
        const int n  = 16 * ct_ + lm_;
        const int k0 = 32 * kt_ + 8 * lq_;
        #pragma unroll
        for (int e = 0; e < 8; ++e) {
            float v = l2w[(size_t)n * HH + k0 + e];
            _Float16 hi = (_Float16)v;
            bcS[0][ct_][kt_][lq_][lm_][e] = hi;
            bcS[1][ct_][kt_][lq_][lm_][e] = (_Float16)(v - (float)hi);
        }
    }

    if (tid < 4) sh_st[tid] = 1;
    ((int*)x2i8)[tid] = 0;    // zero both parities (rows with (l&15)>=8 stay 0)

    // ---- prologue: x0 = leaky(img @ l1w.T + l1b), hi/lo f16 MFMA, K split by r8 ----
    {
        const int m8 = lm & 7;
        const float* arow = img + (size_t)(b0 + m8) * DD + 8 * lq + 2048 * r8;
        const float* brow = l1w + (size_t)ic2 * DD + 8 * lq + 2048 * r8;
        f32x4 z4 = {0.f, 0.f, 0.f, 0.f};
        f32x4 accP0 = z4, accP1 = z4, accQ0 = z4, accQ1 = z4;
        auto ptile = [&](int kt, f32x4& aP, f32x4& aQ) {
            float4 a0  = *(const float4*)(arow + 32 * kt);
            float4 a1  = *(const float4*)(arow + 32 * kt + 4);
            float4 bb0 = *(const float4*)(brow + 32 * kt);
            float4 bb1 = *(const float4*)(brow + 32 * kt + 4);
            f16x8 ah, al, bhf, blf;
            split2s(a0, a1, ah, al);
            split2s(bb0, bb1, bhf, blf);
            f16x8 af = (lm >= 8) ? al : ah;   // lanes lm>=8 carry scaled-lo rows
            aP = __builtin_amdgcn_mfma_f32_16x16x32_f16(af, bhf, aP, 0, 0, 0);
            aQ = __builtin_amdgcn_mfma_f32_16x16x32_f16(af, blf, aQ, 0, 0, 0);
        };
        #pragma unroll 2
        for (int kt = 0; kt < 64; kt += 2) {
            ptile(kt,     accP0, accQ0);
            ptile(kt + 1, accP1, accQ1);
        }
        f32x4 P = accP0 + accP1;
        f32x4 Q = accQ0 + accQ1;
        const float sP = (lane < 32) ? 1.0f : IS10;
        const float sQ = (lane < 32) ? IS10 : IS20;
        float s0 = xsum32(P[0] * sP + Q[0] * sQ);
        float s1 = xsum32(P[1] * sP + Q[1] * sQ);
        float s2 = xsum32(P[2] * sP + Q[2] * sQ);
        float s3 = xsum32(P[3] * sP + Q[3] * sQ);
        if (lane < 32) {     // rows 4lq+reg cover m=0..7; partial for this K half
            float vv[4] = {s0, s1, s2, s3};
            #pragma unroll
            for (int reg = 0; reg < 4; ++reg)
                scr[r8 * 1024 + (4 * lq + reg) * 128 + ic2] = vv[reg];
        }
    }
    __syncthreads();
    {   // combine K halves + bias + leaky: one (m,c) per thread
        const int m = tid >> 7, c = tid & 127;
        float v = scr[m * 128 + c] + scr[1024 + m * 128 + c] + l1b[c];
        xs0[m][c] = (v >= 0.f) ? v : 0.01f * v;
    }
    __syncthreads();

    // phase-A C-row ownership (same as R4): lane holds rows mA, mA+1
    const int mA = (lane < 32) ? 4 * lq : 4 * (lq - 2) + 2;

    // phase-B ownership: one (mB, iB) pair per lane; mB wave-uniform
    const int mB  = w >> 1;
    const int iB  = 64 * (w & 1) + lane;
    const int rBq = 16 * ((iB >> 3) & 3);
    const int cBq = 8 * (iB >> 5) + (iB & 7);
    const int r8q = 16 * ((iB >> 4) & 3) + mB;   // x2i8 row
    const int c8q = 16 * (iB >> 6) + (iB & 15);  // x2i8 byte col
    const unsigned gRd = (unsigned)(mB * 2048 + iB * 16) ^ ((unsigned)(mB & 3) << 5);

    float hreg = 0.f;
    int  len   = TT;
    bool found = false;
    int  tex   = TT;

    // chars(t-1): M-packed MFMA from l2v[slot]; weights from LDS (exact hi+lo)
    auto chars_mfma = [&](int slot, f32x4& cA, f32x4& cB) {
        #pragma unroll
        for (int kt = 0; kt < 4; ++kt) {
            f16x8 cf = *(const f16x8*)&l2v[slot][lane][8 * kt];
            f16x8 bH = *(const f16x8*)&bcS[0][ct][kt][lq][lm][0];
            f16x8 bL = *(const f16x8*)&bcS[1][ct][kt][lq][lm][0];
            f32x4& a = (kt < 2) ? cA : cB;
            a = __builtin_amdgcn_mfma_f32_16x16x32_f16(cf, bH, a, 0, 0, 0);
            a = __builtin_amdgcn_mfma_f32_16x16x32_f16(cf, bL, a, 0, 0, 0);
        }
    };
    auto chars_commit = [&](int slot, f32x4 cA, f32x4 cB) {
        f32x4 ca = cA + cB;
        const int n = 16 * ct + lm;
        float s0 = xsum32(ca[0]);
        float s1 = xsum32(ca[1]);
        float s2 = xsum32(ca[2]);
        float s3 = xsum32(ca[3]);
        scr[slot * 1024 + mA * 128 + n]       = ((lane < 32) ? s0 : s2) + cb;
        scr[slot * 1024 + (mA + 1) * 128 + n] = ((lane < 32) ? s1 : s3) + cb;
    };

    // full-row normalized write of chars(tme) for batch row r from scr slot
    auto outrow = [&](int slot, int tme, int r) {
        const float* cr = &scr[slot * 1024 + r * 128];
        float a0 = cr[lane];
        float a1 = cr[32 + lane];
        float a2 = cr[64 + lane];
        float mx = fmaxf(fmaxf(a0, a1), a2);
        mx = fmaxf(mx, __shfl_xor(mx, 16, 32));
        mx = fmaxf(mx, __shfl_xor(mx, 8, 32));
        mx = fmaxf(mx, __shfl_xor(mx, 4, 32));
        mx = fmaxf(mx, __shfl_xor(mx, 2, 32));
        mx = fmaxf(mx, __shfl_xor(mx, 1, 32));
        float q0 = a0 / mx;   // exact IEEE divide (q52 == 1.0f check + stored bits)
        float q1 = a1 / mx;
        float q2 = a2 / mx;
        if (lane < 32) {
            size_t base = ((size_t)(b0 + r) * TT + tme) * CC;
            out[base + lane]      = (q0 > THRV) ? q0 : 0.f;
            out[base + 32 + lane] = (q1 > THRV) ? q1 : 0.f;
            out[base + 64 + lane] = (q2 > THRV) ? q2 : 0.f;
        }
        float q52 = __shfl(q1, 20, 64);   // element 52 = 32 + 20
        if (!found && q52 == 1.0f) { found = true; len = tme + 1; }
    };

    for (int t = 0; t < TT; ++t) {
        const int pr = (t + 1) & 1;   // read slot ((t-1)&1)
        const int pc = t & 1;         // write slot

        // ================= phase A =================
        if (t == 0) {
            // exact-f32 gates from xs0 -> gEx (wih only for g<3; h=0 -> g=3 bias)
            if (tid < 512) {
                const int g = tid >> 7;        // 0..3
                const int i = tid & 127;
                float bsum;
                if (g == 0)      bsum = bih[i] + bhh[i];
                else if (g == 1) bsum = bih[128 + i] + bhh[128 + i];
                else if (g == 2) bsum = bih[256 + i];
                else             bsum = bhh[256 + i];
                float accT[NB];
                #pragma unroll
                for (int m = 0; m < NB; ++m) accT[m] = bsum;
                if (g < 3) {
                    const float4* wp = (const float4*)(wih + (size_t)(128 * g + i) * HH);
                    #pragma unroll
                    for (int k = 0; k < HH / 4; ++k) {
                        float4 wv = wp[k];
                        #pragma unroll
                        for (int m = 0; m < NB; ++m) {
                            float4 x = *(const float4*)&xs0[m][4 * k];
                            accT[m] += wv.x * x.x + wv.y * x.y + wv.z * x.z + wv.w * x.w;
                        }
                    }
                }
                #pragma unroll
                for (int m = 0; m < NB; ++m) {
                    unsigned off = (unsigned)(m * 2048 + i * 16 + g * 4) ^ ((unsigned)(m & 3) << 5);
                    *(float*)((char*)gEx + off) = accT[m];
                }
            }
        } else {
            // gates first: A-frag loads + 8 f16 MFMA (2 gates, hi-B; M-pack gives
            // ah*bh + al*bh) + 4 i8 MFMA (ah*bl correction, K=64)
            f16x8 af0 = *(const f16x8*)&x2[pr][lane][0];
            f16x8 af1 = *(const f16x8*)&x2[pr][lane][8];
            f16x8 af2 = *(const f16x8*)&x2[pr][lane][16];
            f16x8 af3 = *(const f16x8*)&x2[pr][lane][24];
            i32x4 ia0 = *(const i32x4*)&x2i8[pr][lane][0];
            i32x4 ia1 = *(const i32x4*)&x2i8[pr][lane][16];
            f32x4 z4 = {0.f, 0.f, 0.f, 0.f};
            i32x4 iz = {0, 0, 0, 0};
            f32x4 aA[2] = {z4, z4};
            f32x4 aB[2] = {z4, z4};
            i32x4 qac[2] = {iz, iz};
            #pragma unroll
            for (int gl = 0; gl < 2; ++gl) {
                aA[gl] = __builtin_amdgcn_mfma_f32_16x16x32_f16(af0, bh[gl][0], aA[gl], 0, 0, 0);
                aA[gl] = __builtin_amdgcn_mfma_f32_16x16x32_f16(af1, bh[gl][1], aA[gl], 0, 0, 0);
                aB[gl] = __builtin_amdgcn_mfma_f32_16x16x32_f16(af2, bh[gl][2], aB[gl], 0, 0, 0);
                aB[gl] = __builtin_amdgcn_mfma_f32_16x16x32_f16(af3, bh[gl][3], aB[gl], 0, 0, 0);
                qac[gl] = __builtin_amdgcn_mfma_i32_16x16x64_i8(ia0, bq[gl][0], qac[gl], 0, 0, 0);
                qac[gl] = __builtin_amdgcn_mfma_i32_16x16x64_i8(ia1, bq[gl][1], qac[gl], 0, 0, 0);
            }
            // chars(t-1) under the gate-MFMA shadow (waves 1..6)
            f32x4 cc0 = z4, cc1 = z4;
            if (ct >= 0) chars_mfma(pr, cc0, cc1);
            // gate combine (hi rows + lo rows via lane^32) + i8 corr + exchange write
            float G[2][2];
            #pragma unroll
            for (int gl = 0; gl < 2; ++gl) {
                f32x4 s4 = aA[gl] + aB[gl];
                float s0 = xsum32(s4[0]);
                float s1 = xsum32(s4[1]);
                float s2 = xsum32(s4[2]);
                float s3 = xsum32(s4[3]);
                float q0 = xsum32((float)qac[gl][0]);   // i8 rows 8-15 are zero;
                float q1 = xsum32((float)qac[gl][1]);   // xsum32 mirrors rows 0-7
                float q2 = xsum32((float)qac[gl][2]);
                float q3 = xsum32((float)qac[gl][3]);
                G[gl][0] = ((lane < 32) ? s0 : s2) + ((lane < 32) ? q0 : q2) * fq[gl] + gb[gl];
                G[gl][1] = ((lane < 32) ? s1 : s3) + ((lane < 32) ? q1 : q3) * fq[gl] + gb[gl];
            }
            #pragma unroll
            for (int s = 0; s < 2; ++s) {
                const int m = mA + s;
                unsigned off = (unsigned)(m * 2048 + ic2 * 16 + r8 * 8) ^ ((unsigned)(m & 3) << 5);
                f32x2 v2 = {G[0][s], G[1][s]};
                *(f32x2*)((char*)gEx + off) = v2;
            }
            if (ct >= 0) chars_commit(pr, cc0, cc1);
        }
        step_barrier();   // bar1: gEx (and chs) ready

        // ================= phase B =================
        {
            float4 g4 = *(const float4*)((const char*)gEx + gRd);
            float r = sigm(g4.x);
            float z = sigm(g4.y);
            float n = ftanh(g4.z + r * g4.w);
            float hp = (t == 0) ? 0.f : hreg;
            float h  = (1.f - z) * n + z * hp;
            bool chg = (t < 2) | (fabsf(h - hp) > HEPS);
            hreg = h;
            float lv = (h >= 0.f) ? h : 0.01f * h;
            _Float16 a, b;
            split1(h, a, b);
            x2[pc][rBq + mB][cBq]     = a;
            x2[pc][rBq + 8 + mB][cBq] = b;
            split1(lv, a, b);
            l2v[pc][rBq + mB][cBq]     = a;
            l2v[pc][rBq + 8 + mB][cBq] = b;
            x2i8[pc][r8q][c8q] = (char)(int)rintf(h * 127.0f);   // |h| < 1
            if (chg) sh_st[t & 3] = 0;          // benign multi-writer race
        }
        if (w >= 8 && t >= 2) outrow(pc, t - 2, w - 8);
        if (tid == 0) sh_st[(t + 2) & 3] = 1;   // slot for t+2
        step_barrier();   // bar2: x2/l2v ready for next step
        if (t >= 2 && sh_st[t & 3]) { tex = t; break; }
    }

    if (tex == TT) {
        // natural end: write chars(TT-2); compute + write chars(TT-1)
        const int pl = (TT - 1) & 1;
        if (ct >= 0) {
            f32x4 z4 = {0.f, 0.f, 0.f, 0.f};
            f32x4 cc0 = z4, cc1 = z4;
            chars_mfma(pl, cc0, cc1);
            chars_commit(pl, cc0, cc1);
        }
        if (w >= 8) outrow(TT & 1, TT - 2, w - 8);
        __syncthreads();
        if (w >= 8) outrow(pl, TT - 1, w - 8);
    } else if (w >= 8) {
        // frozen from tex: loop wrote times 0..tex-2. Write chars(tex-1), then
        // fill [tex, TT) with the two parity patterns (zeros included), stride-2.
        const int r = w - 8;
        outrow((tex + 1) & 1, tex - 1, r);
        size_t rowbase = (size_t)(b0 + r) * TT * CC;
        #pragma unroll
        for (int p = 0; p < 2; ++p) {
            const float* cr = &scr[p * 1024 + r * 128];
            float a0 = cr[lane];
            float a1 = cr[32 + lane];
            float a2 = cr[64 + lane];
            float mx = fmaxf(fmaxf(a0, a1), a2);
            mx = fmaxf(mx, __shfl_xor(mx, 16, 32));
            mx = fmaxf(mx, __shfl_xor(mx, 8, 32));
            mx = fmaxf(mx, __shfl_xor(mx, 4, 32));
            mx = fmaxf(mx, __shfl_xor(mx, 2, 32));
            mx = fmaxf(mx, __shfl_xor(mx, 1, 32));
            const int u0 = tex + (((tex & 1) == p) ? 0 : 1);
            if (lane < 32) {
                float q0 = a0 / mx;
                float q1 = a1 / mx;
                float q2 = a2 / mx;
                float w0v = (q0 > THRV) ? q0 : 0.f;
                float w1v = (q1 > THRV) ? q1 : 0.f;
                float w2v = (q2 > THRV) ? q2 : 0.f;
                for (int u = u0; u < TT; u += 2) {
                    out[rowbase + (size_t)u * CC + lane]      = w0v;
                    out[rowbase + (size_t)u * CC + 32 + lane] = w1v;
                    out[rowbase + (size_t)u * CC + 64 + lane] = w2v;
                }
            }
        }
        // lens: frozen pattern's char-52 hit (if any) recorded at tex-2 / tex-1.
    }

    if (w >= 8 && lane == 0) lens[b0 + (w - 8)] = (float)len;
}

extern "C" void kernel_launch(void* const* d_in, const int* in_sizes, int n_in,
                              void* d_out, int out_size, void* d_ws, size_t ws_size,
                              hipStream_t stream)
{
    const float* img = (const float*)d_in[0];
    const float* l1w = (const float*)d_in[1];
    const float* l1b = (const float*)d_in[2];
    const float* wih = (const float*)d_in[3];
    const float* whh = (const float*)d_in[4];
    const float* bih = (const float*)d_in[5];
    const float* bhh = (const float*)d_in[6];
    const float* l2w = (const float*)d_in[7];
    const float* l2b = (const float*)d_in[8];

    float* out  = (float*)d_out;
    float* lens = out + (size_t)2048 * TT * CC;

    // no memset: the kernel writes every title element exactly once
    // (full-row coalesced stores with explicit zeros) and all lens entries.
    gru_title<<<dim3(2048 / NB), dim3(1024), 0, stream>>>(
        img, l1w, l1b, wih, whh, bih, bhh, l2w, l2b, out, lens);
}

// Round 9
// 581.230 us; speedup vs baseline: 1.1955x; 1.1955x over previous
//
#include <hip/hip_runtime.h>
#include <math.h>

#define NB   8
#define TT   400
#define HH   128
#define CC   96
#define DD   4096
#define THRV (1.0f - 1e-5f)
#define XR   40      // f16 row pad: 80 B rows (5*16B -> b128-aligned, clean bank walk)
#define HEPS 4e-6f   // convergence tolerance (same class-proven margin as before)
#define S10  1024.0f            // lo-split scale (keeps lo out of f16 subnormals)
#define IS10 0.0009765625f      // 2^-10
#define IS20 9.5367431640625e-07f  // 2^-20

typedef _Float16 f16x8 __attribute__((ext_vector_type(8)));
typedef float    f32x4 __attribute__((ext_vector_type(4)));
typedef float    f32x2 __attribute__((ext_vector_type(2)));
typedef int      i32x4 __attribute__((ext_vector_type(4)));
typedef unsigned long long ull;

__device__ __forceinline__ float rcp_fast(float x) {
#if __has_builtin(__builtin_amdgcn_rcpf)
    return __builtin_amdgcn_rcpf(x);
#else
    return 1.0f / x;
#endif
}
// v_exp_f32-based sigmoid/tanh: ~1e-7 err, far inside the proven 5e-5 margin.
__device__ __forceinline__ float sigm(float v)  { return rcp_fast(1.0f + __expf(-v)); }
__device__ __forceinline__ float ftanh(float x) { return 1.0f - 2.0f * rcp_fast(1.0f + __expf(2.0f * x)); }

__device__ __forceinline__ void split2(float4 u0, float4 u1, f16x8& hi, f16x8& lo) {
    float x[8] = {u0.x, u0.y, u0.z, u0.w, u1.x, u1.y, u1.z, u1.w};
    #pragma unroll
    for (int e = 0; e < 8; ++e) {
        _Float16 h = (_Float16)x[e];
        hi[e] = h;
        lo[e] = (_Float16)(x[e] - (float)h);
    }
}
// scaled variant: lo is stored *1024 so residuals stay in f16 normal range
__device__ __forceinline__ void split2s(float4 u0, float4 u1, f16x8& hi, f16x8& lo) {
    float x[8] = {u0.x, u0.y, u0.z, u0.w, u1.x, u1.y, u1.z, u1.w};
    #pragma unroll
    for (int e = 0; e < 8; ++e) {
        _Float16 h = (_Float16)x[e];
        hi[e] = h;
        lo[e] = (_Float16)((x[e] - (float)h) * S10);
    }
}
__device__ __forceinline__ void split1(float x, _Float16& hi, _Float16& lo) {
    hi = (_Float16)x;
    lo = (_Float16)(x - (float)hi);
}

// lane ^ 32 combine on the VALU pipe (keeps the LDS pipe free)
__device__ __forceinline__ float xsum32(float v) {
#if __has_builtin(__builtin_amdgcn_permlane32_swap)
    auto r = __builtin_amdgcn_permlane32_swap(__float_as_uint(v), __float_as_uint(v), false, false);
    return __uint_as_float(r[0]) + __uint_as_float(r[1]);
#else
    return v + __shfl_xor(v, 32, 64);
#endif
}

// Barrier WITHOUT the vmcnt(0) drain __syncthreads would emit: global stores
// (out[]) are fire-and-forget (nothing reads them), so only LDS ops need to
// complete before waves cross.
__device__ __forceinline__ void step_barrier() {
    __builtin_amdgcn_sched_barrier(0);
    asm volatile("s_waitcnt lgkmcnt(0)" ::: "memory");
    __builtin_amdgcn_s_barrier();
    asm volatile("" ::: "memory");
    __builtin_amdgcn_sched_barrier(0);
}

__global__ __launch_bounds__(1024, 4)
void gru_title(const float* __restrict__ img,
               const float* __restrict__ l1w,
               const float* __restrict__ l1b,
               const float* __restrict__ wih,
               const float* __restrict__ whh,
               const float* __restrict__ bih,
               const float* __restrict__ bhh,
               const float* __restrict__ l2w,
               const float* __restrict__ l2b,
               float* __restrict__ out,
               float* __restrict__ lens)
{
    // M-packed A layout (proven in R4/R5): value (m,k,hi) at row 16*((k>>3)&3)+m,
    // lo at +8; f16 col 8*(k>>5)+(k&7). A-frag read = row=lane, col=8*kt.
    __shared__ alignas(16) _Float16 x2 [2][64][XR];   // h: hi rows 0-7, lo rows 8-15 per 16-group
    __shared__ alignas(16) _Float16 l2v[2][64][XR];   // leaky(h), same layout
    __shared__ alignas(16) char     x2i8[2][64][32];  // i8(h*127): rows (l&15)<8 data, rest 0
    __shared__ alignas(16) _Float16 bcS[2][6][4][4][16][8]; // chars weights hi(0)/lo(1), 48 KB
    __shared__ alignas(16) float    gEx[4096];        // gate exchange [m][i][g], XOR ((m&3)<<5)
    __shared__ alignas(16) float    scr[2048];        // chs[2][8][128]  UNION  xsP[2][8][128]
    __shared__ alignas(16) float    xs0[NB][HH];      // x0 (t=0 path)
    __shared__ int sh_st[4];                          // stable flags, 4-slot rotation

    const int tid  = threadIdx.x;
    const int b0   = blockIdx.x * NB;
    const int w    = tid >> 6;     // wave 0..15
    const int lane = tid & 63;
    const int lm   = lane & 15;
    const int lq   = lane >> 4;
    const int c8   = w & 7;        // i-chunk [16*c8, 16*c8+16)
    const int r8   = w >> 3;       // gate-pair half: 0 -> gates {r,z}, 1 -> {n_i,n_h}
    const int ic2  = 16 * c8 + lm;

    // ---- gate weights: this wave owns gates {2r8, 2r8+1} for chunk c8 ----
    // g=0: r (wih+whh fused, x==h for t>=1); g=1: z (fused); g=2: n_i; g=3: n_h
    // B hi in f16 frags; the ah*bl term is restored via an i8 MFMA correction
    // (K=64, 2 MFMAs/gate): h->i8 (A, built in phase B), bl->i8 with per-column
    // scale (B, built here). Residual error ~1e-5 per gate pre-act.
    f16x8 bh[2][4];
    i32x4 bq[2][2];
    float gb[2], fq[2];
    #pragma unroll
    for (int gl = 0; gl < 2; ++gl) {
        const int g2 = 2 * r8 + gl;
        const float* r0;
        const float* r1 = nullptr;
        float bsum;
        if (g2 == 0)      { r0 = wih + (size_t)ic2 * HH;         r1 = whh + (size_t)ic2 * HH;         bsum = bih[ic2] + bhh[ic2]; }
        else if (g2 == 1) { r0 = wih + (size_t)(128 + ic2) * HH; r1 = whh + (size_t)(128 + ic2) * HH; bsum = bih[128 + ic2] + bhh[128 + ic2]; }
        else if (g2 == 2) { r0 = wih + (size_t)(256 + ic2) * HH;                                      bsum = bih[256 + ic2]; }
        else              { r0 = whh + (size_t)(256 + ic2) * HH;                                      bsum = bhh[256 + ic2]; }
        gb[gl] = bsum;
        float bl32[4][8];
        #pragma unroll
        for (int kt = 0; kt < 4; ++kt) {
            const int k0 = 32 * kt + 8 * lq;
            float4 u0 = *(const float4*)(r0 + k0);
            float4 u1 = *(const float4*)(r0 + k0 + 4);
            if (r1) {
                float4 e0 = *(const float4*)(r1 + k0);
                float4 e1 = *(const float4*)(r1 + k0 + 4);
                u0.x += e0.x; u0.y += e0.y; u0.z += e0.z; u0.w += e0.w;
                u1.x += e1.x; u1.y += e1.y; u1.z += e1.z; u1.w += e1.w;
            }
            float xv[8] = {u0.x, u0.y, u0.z, u0.w, u1.x, u1.y, u1.z, u1.w};
            f16x8 hiv;
            #pragma unroll
            for (int e = 0; e < 8; ++e) {
                _Float16 hh = (_Float16)xv[e];
                hiv[e] = hh;
                bl32[kt][e] = xv[e] - (float)hh;   // f32 residual (f16 would be subnormal)
            }
            bh[gl][kt] = hiv;
        }
        // per-column |bl| max across all K (this lane holds k = 32kt+8lq+e; the
        // 4 lanes sharing lm (lq=0..3) cover the column)
        float mx = 0.f;
        #pragma unroll
        for (int kt = 0; kt < 4; ++kt)
            #pragma unroll
            for (int e = 0; e < 8; ++e) mx = fmaxf(mx, fabsf(bl32[kt][e]));
        mx = fmaxf(mx, __shfl_xor(mx, 16, 64));
        mx = fmaxf(mx, __shfl_xor(mx, 32, 64));
        const float inv = (mx > 0.f) ? 127.0f / mx : 0.f;
        fq[gl] = mx * (1.0f / 16129.0f);   // dequant: (q_a q_b) * mx/(127*127)
        // quantize + pack own 8 bytes per kt (byte e = k 32kt+8lq+e, LSB-first)
        ull p[4];
        #pragma unroll
        for (int kt = 0; kt < 4; ++kt) {
            ull pv = 0;
            #pragma unroll
            for (int e = 0; e < 8; ++e) {
                int q = (int)rintf(bl32[kt][e] * inv);
                pv |= ((ull)((unsigned)q & 0xffu)) << (8 * e);
            }
            p[kt] = pv;
        }
        // gather into i8 B-frag order: frag kt' byte b <-> k = 64kt'+16lq+b.
        // src = lane (lm, (2lq+(b>=8))&3), p-index 2kt'+(lq>>1). Double-shuffle
        // (uniform indices) + select by lq&2.
        #pragma unroll
        for (int ktp = 0; ktp < 2; ++ktp) {
            ull s0a = __shfl(p[2 * ktp],     lm + 16 * ((2 * lq) & 3), 64);
            ull s0b = __shfl(p[2 * ktp + 1], lm + 16 * ((2 * lq) & 3), 64);
            ull lo8 = (lq & 2) ? s0b : s0a;
            ull s1a = __shfl(p[2 * ktp],     lm + 16 * ((2 * lq + 1) & 3), 64);
            ull s1b = __shfl(p[2 * ktp + 1], lm + 16 * ((2 * lq + 1) & 3), 64);
            ull hi8 = (lq & 2) ? s1b : s1a;
            i32x4 f;
            f[0] = (int)(unsigned)(lo8 & 0xffffffffu);
            f[1] = (int)(unsigned)(lo8 >> 32);
            f[2] = (int)(unsigned)(hi8 & 0xffffffffu);
            f[3] = (int)(unsigned)(hi8 >> 32);
            bq[gl][ktp] = f;
        }
    }

    // ---- chars: waves 1..6 own tile ct = w-1 (weights live in LDS; EXACT hi+lo) ----
    const int ct = (w >= 1 && w <= 6) ? (w - 1) : -1;
    float cb = 0.f;
    if (ct >= 0) cb = l2b[16 * ct + lm];

    // stage chars weights (hi + lo planes) in LDS; all threads help
    for (int idx = tid; idx < 6 * 4 * 4 * 16; idx += 1024) {
        int t_  = idx;
        int lm_ = t_ & 15; t_ >>= 4;
        int lq_ = t_ & 3;  t_ >>= 2;
        int kt_ = t_ & 3;  t_ >>= 2;
        int ct_ = t_;                       // 0..5
        const int n  = 16 * ct_ + lm_;
        const int k0 = 32 * kt_ + 8 * lq_;
        #pragma unroll
        for (int e = 0; e < 8; ++e) {
            float v = l2w[(size_t)n * HH + k0 + e];
            _Float16 hi = (_Float16)v;
            bcS[0][ct_][kt_][lq_][lm_][e] = hi;
            bcS[1][ct_][kt_][lq_][lm_][e] = (_Float16)(v - (float)hi);
        }
    }

    if (tid < 4) sh_st[tid] = 1;
    ((int*)x2i8)[tid] = 0;    // zero both parities (rows with (l&15)>=8 stay 0)

    // ---- prologue: x0 = leaky(img @ l1w.T + l1b), hi/lo f16 MFMA, K split by r8 ----
    {
        const int m8 = lm & 7;
        const float* arow = img + (size_t)(b0 + m8) * DD + 8 * lq + 2048 * r8;
        const float* brow = l1w + (size_t)ic2 * DD + 8 * lq + 2048 * r8;
        f32x4 z4 = {0.f, 0.f, 0.f, 0.f};
        f32x4 accP0 = z4, accP1 = z4, accQ0 = z4, accQ1 = z4;
        auto ptile = [&](int kt, f32x4& aP, f32x4& aQ) {
            float4 a0  = *(const float4*)(arow + 32 * kt);
            float4 a1  = *(const float4*)(arow + 32 * kt + 4);
            float4 bb0 = *(const float4*)(brow + 32 * kt);
            float4 bb1 = *(const float4*)(brow + 32 * kt + 4);
            f16x8 ah, al, bhf, blf;
            split2s(a0, a1, ah, al);
            split2s(bb0, bb1, bhf, blf);
            f16x8 af = (lm >= 8) ? al : ah;   // lanes lm>=8 carry scaled-lo rows
            aP = __builtin_amdgcn_mfma_f32_16x16x32_f16(af, bhf, aP, 0, 0, 0);
            aQ = __builtin_amdgcn_mfma_f32_16x16x32_f16(af, blf, aQ, 0, 0, 0);
        };
        #pragma unroll 2
        for (int kt = 0; kt < 64; kt += 2) {
            ptile(kt,     accP0, accQ0);
            ptile(kt + 1, accP1, accQ1);
        }
        f32x4 P = accP0 + accP1;
        f32x4 Q = accQ0 + accQ1;
        const float sP = (lane < 32) ? 1.0f : IS10;
        const float sQ = (lane < 32) ? IS10 : IS20;
        float s0 = xsum32(P[0] * sP + Q[0] * sQ);
        float s1 = xsum32(P[1] * sP + Q[1] * sQ);
        float s2 = xsum32(P[2] * sP + Q[2] * sQ);
        float s3 = xsum32(P[3] * sP + Q[3] * sQ);
        if (lane < 32) {     // rows 4lq+reg cover m=0..7; partial for this K half
            float vv[4] = {s0, s1, s2, s3};
            #pragma unroll
            for (int reg = 0; reg < 4; ++reg)
                scr[r8 * 1024 + (4 * lq + reg) * 128 + ic2] = vv[reg];
        }
    }
    __syncthreads();
    {   // combine K halves + bias + leaky: one (m,c) per thread
        const int m = tid >> 7, c = tid & 127;
        float v = scr[m * 128 + c] + scr[1024 + m * 128 + c] + l1b[c];
        xs0[m][c] = (v >= 0.f) ? v : 0.01f * v;
    }
    __syncthreads();

    // phase-A C-row ownership (same as R4): lane holds rows mA, mA+1
    const int mA = (lane < 32) ? 4 * lq : 4 * (lq - 2) + 2;

    // phase-B ownership: one (mB, iB) pair per lane; mB wave-uniform
    const int mB  = w >> 1;
    const int iB  = 64 * (w & 1) + lane;
    const int rBq = 16 * ((iB >> 3) & 3);
    const int cBq = 8 * (iB >> 5) + (iB & 7);
    const int r8q = 16 * ((iB >> 4) & 3) + mB;   // x2i8 row
    const int c8q = 16 * (iB >> 6) + (iB & 15);  // x2i8 byte col
    const unsigned gRd = (unsigned)(mB * 2048 + iB * 16) ^ ((unsigned)(mB & 3) << 5);

    float hreg = 0.f;
    int  len   = TT;
    bool found = false;
    int  tex   = TT;

    // chars(t-1): M-packed MFMA from l2v[slot]; weights from LDS (exact hi+lo)
    auto chars_mfma = [&](int slot, f32x4& cA, f32x4& cB) {
        #pragma unroll
        for (int kt = 0; kt < 4; ++kt) {
            f16x8 cf = *(const f16x8*)&l2v[slot][lane][8 * kt];
            f16x8 bH = *(const f16x8*)&bcS[0][ct][kt][lq][lm][0];
            f16x8 bL = *(const f16x8*)&bcS[1][ct][kt][lq][lm][0];
            f32x4& a = (kt < 2) ? cA : cB;
            a = __builtin_amdgcn_mfma_f32_16x16x32_f16(cf, bH, a, 0, 0, 0);
            a = __builtin_amdgcn_mfma_f32_16x16x32_f16(cf, bL, a, 0, 0, 0);
        }
    };
    auto chars_commit = [&](int slot, f32x4 cA, f32x4 cB) {
        f32x4 ca = cA + cB;
        const int n = 16 * ct + lm;
        float s0 = xsum32(ca[0]);
        float s1 = xsum32(ca[1]);
        float s2 = xsum32(ca[2]);
        float s3 = xsum32(ca[3]);
        scr[slot * 1024 + mA * 128 + n]       = ((lane < 32) ? s0 : s2) + cb;
        scr[slot * 1024 + (mA + 1) * 128 + n] = ((lane < 32) ? s1 : s3) + cb;
    };

    // full-row normalized write of chars(tme) for batch row r from scr slot
    auto outrow = [&](int slot, int tme, int r) {
        const float* cr = &scr[slot * 1024 + r * 128];
        float a0 = cr[lane];
        float a1 = cr[32 + lane];
        float a2 = cr[64 + lane];
        float mx = fmaxf(fmaxf(a0, a1), a2);
        mx = fmaxf(mx, __shfl_xor(mx, 16, 32));
        mx = fmaxf(mx, __shfl_xor(mx, 8, 32));
        mx = fmaxf(mx, __shfl_xor(mx, 4, 32));
        mx = fmaxf(mx, __shfl_xor(mx, 2, 32));
        mx = fmaxf(mx, __shfl_xor(mx, 1, 32));
        float q0 = a0 / mx;   // exact IEEE divide (q52 == 1.0f check + stored bits)
        float q1 = a1 / mx;
        float q2 = a2 / mx;
        if (lane < 32) {
            size_t base = ((size_t)(b0 + r) * TT + tme) * CC;
            out[base + lane]      = (q0 > THRV) ? q0 : 0.f;
            out[base + 32 + lane] = (q1 > THRV) ? q1 : 0.f;
            out[base + 64 + lane] = (q2 > THRV) ? q2 : 0.f;
        }
        float q52 = __shfl(q1, 20, 64);   // element 52 = 32 + 20
        if (!found && q52 == 1.0f) { found = true; len = tme + 1; }
    };

    for (int t = 0; t < TT; ++t) {
        const int pr = (t + 1) & 1;   // read slot ((t-1)&1)
        const int pc = t & 1;         // write slot

        // ================= phase A =================
        if (t == 0) {
            // exact-f32 gates from xs0 -> gEx (wih only for g<3; h=0 -> g=3 bias)
            if (tid < 512) {
                const int g = tid >> 7;        // 0..3
                const int i = tid & 127;
                float bsum;
                if (g == 0)      bsum = bih[i] + bhh[i];
                else if (g == 1) bsum = bih[128 + i] + bhh[128 + i];
                else if (g == 2) bsum = bih[256 + i];
                else             bsum = bhh[256 + i];
                float accT[NB];
                #pragma unroll
                for (int m = 0; m < NB; ++m) accT[m] = bsum;
                if (g < 3) {
                    const float4* wp = (const float4*)(wih + (size_t)(128 * g + i) * HH);
                    #pragma unroll
                    for (int k = 0; k < HH / 4; ++k) {
                        float4 wv = wp[k];
                        #pragma unroll
                        for (int m = 0; m < NB; ++m) {
                            float4 x = *(const float4*)&xs0[m][4 * k];
                            accT[m] += wv.x * x.x + wv.y * x.y + wv.z * x.z + wv.w * x.w;
                        }
                    }
                }
                #pragma unroll
                for (int m = 0; m < NB; ++m) {
                    unsigned off = (unsigned)(m * 2048 + i * 16 + g * 4) ^ ((unsigned)(m & 3) << 5);
                    *(float*)((char*)gEx + off) = accT[m];
                }
            }
        } else {
            f32x4 z4 = {0.f, 0.f, 0.f, 0.f};
            i32x4 iz = {0, 0, 0, 0};
            // ---- chars(t-1) FIRST (waves 1..6): its live-set window closes
            // before the gate live-set opens -> peak regs = max, not sum ----
            if (ct >= 0) {
                f32x4 cc0 = z4, cc1 = z4;
                chars_mfma(pr, cc0, cc1);
                chars_commit(pr, cc0, cc1);
            }
            // ---- gates: paired A-frag loads (2 live at a time), ONE acc/gate,
            // i8 frags loaded one at a time; fused f16+i8 combine ----
            f32x4 acc[2] = {z4, z4};
            i32x4 qac[2] = {iz, iz};
            {
                f16x8 afA = *(const f16x8*)&x2[pr][lane][0];
                f16x8 afB = *(const f16x8*)&x2[pr][lane][8];
                acc[0] = __builtin_amdgcn_mfma_f32_16x16x32_f16(afA, bh[0][0], acc[0], 0, 0, 0);
                acc[1] = __builtin_amdgcn_mfma_f32_16x16x32_f16(afA, bh[1][0], acc[1], 0, 0, 0);
                acc[0] = __builtin_amdgcn_mfma_f32_16x16x32_f16(afB, bh[0][1], acc[0], 0, 0, 0);
                acc[1] = __builtin_amdgcn_mfma_f32_16x16x32_f16(afB, bh[1][1], acc[1], 0, 0, 0);
                afA = *(const f16x8*)&x2[pr][lane][16];
                afB = *(const f16x8*)&x2[pr][lane][24];
                acc[0] = __builtin_amdgcn_mfma_f32_16x16x32_f16(afA, bh[0][2], acc[0], 0, 0, 0);
                acc[1] = __builtin_amdgcn_mfma_f32_16x16x32_f16(afA, bh[1][2], acc[1], 0, 0, 0);
                acc[0] = __builtin_amdgcn_mfma_f32_16x16x32_f16(afB, bh[0][3], acc[0], 0, 0, 0);
                acc[1] = __builtin_amdgcn_mfma_f32_16x16x32_f16(afB, bh[1][3], acc[1], 0, 0, 0);
                i32x4 ia = *(const i32x4*)&x2i8[pr][lane][0];
                qac[0] = __builtin_amdgcn_mfma_i32_16x16x64_i8(ia, bq[0][0], qac[0], 0, 0, 0);
                qac[1] = __builtin_amdgcn_mfma_i32_16x16x64_i8(ia, bq[1][0], qac[1], 0, 0, 0);
                ia = *(const i32x4*)&x2i8[pr][lane][16];
                qac[0] = __builtin_amdgcn_mfma_i32_16x16x64_i8(ia, bq[0][1], qac[0], 0, 0, 0);
                qac[1] = __builtin_amdgcn_mfma_i32_16x16x64_i8(ia, bq[1][1], qac[1], 0, 0, 0);
            }
            // fused combine: xsum32(s) + fq*xsum32(q) == xsum32(s + fq*q)
            // (fq uniform across lane^32 pair; i8 rows 8-15 are zero)
            float G[2][2];
            #pragma unroll
            for (int gl = 0; gl < 2; ++gl) {
                f32x4 t4;
                #pragma unroll
                for (int rr = 0; rr < 4; ++rr)
                    t4[rr] = acc[gl][rr] + fq[gl] * (float)qac[gl][rr];
                float c0 = xsum32(t4[0]);
                float c1 = xsum32(t4[1]);
                float c2 = xsum32(t4[2]);
                float c3 = xsum32(t4[3]);
                G[gl][0] = ((lane < 32) ? c0 : c2) + gb[gl];
                G[gl][1] = ((lane < 32) ? c1 : c3) + gb[gl];
            }
            #pragma unroll
            for (int s = 0; s < 2; ++s) {
                const int m = mA + s;
                unsigned off = (unsigned)(m * 2048 + ic2 * 16 + r8 * 8) ^ ((unsigned)(m & 3) << 5);
                f32x2 v2 = {G[0][s], G[1][s]};
                *(f32x2*)((char*)gEx + off) = v2;
            }
        }
        step_barrier();   // bar1: gEx (and chs) ready

        // ================= phase B =================
        {
            float4 g4 = *(const float4*)((const char*)gEx + gRd);
            float r = sigm(g4.x);
            float z = sigm(g4.y);
            float n = ftanh(g4.z + r * g4.w);
            float hp = (t == 0) ? 0.f : hreg;
            float h  = (1.f - z) * n + z * hp;
            bool chg = (t < 2) | (fabsf(h - hp) > HEPS);
            hreg = h;
            float lv = (h >= 0.f) ? h : 0.01f * h;
            _Float16 a, b;
            split1(h, a, b);
            x2[pc][rBq + mB][cBq]     = a;
            x2[pc][rBq + 8 + mB][cBq] = b;
            split1(lv, a, b);
            l2v[pc][rBq + mB][cBq]     = a;
            l2v[pc][rBq + 8 + mB][cBq] = b;
            x2i8[pc][r8q][c8q] = (char)(int)rintf(h * 127.0f);   // |h| < 1
            if (chg) sh_st[t & 3] = 0;          // benign multi-writer race
        }
        if (w >= 8 && t >= 2) outrow(pc, t - 2, w - 8);
        if (tid == 0) sh_st[(t + 2) & 3] = 1;   // slot for t+2
        step_barrier();   // bar2: x2/l2v ready for next step
        if (t >= 2 && sh_st[t & 3]) { tex = t; break; }
    }

    if (tex == TT) {
        // natural end: write chars(TT-2); compute + write chars(TT-1)
        const int pl = (TT - 1) & 1;
        if (ct >= 0) {
            f32x4 z4 = {0.f, 0.f, 0.f, 0.f};
            f32x4 cc0 = z4, cc1 = z4;
            chars_mfma(pl, cc0, cc1);
            chars_commit(pl, cc0, cc1);
        }
        if (w >= 8) outrow(TT & 1, TT - 2, w - 8);
        __syncthreads();
        if (w >= 8) outrow(pl, TT - 1, w - 8);
    } else if (w >= 8) {
        // frozen from tex: loop wrote times 0..tex-2. Write chars(tex-1), then
        // fill [tex, TT) with the two parity patterns (zeros included), stride-2.
        const int r = w - 8;
        outrow((tex + 1) & 1, tex - 1, r);
        size_t rowbase = (size_t)(b0 + r) * TT * CC;
        #pragma unroll
        for (int p = 0; p < 2; ++p) {
            const float* cr = &scr[p * 1024 + r * 128];
            float a0 = cr[lane];
            float a1 = cr[32 + lane];
            float a2 = cr[64 + lane];
            float mx = fmaxf(fmaxf(a0, a1), a2);
            mx = fmaxf(mx, __shfl_xor(mx, 16, 32));
            mx = fmaxf(mx, __shfl_xor(mx, 8, 32));
            mx = fmaxf(mx, __shfl_xor(mx, 4, 32));
            mx = fmaxf(mx, __shfl_xor(mx, 2, 32));
            mx = fmaxf(mx, __shfl_xor(mx, 1, 32));
            const int u0 = tex + (((tex & 1) == p) ? 0 : 1);
            if (lane < 32) {
                float q0 = a0 / mx;
                float q1 = a1 / mx;
                float q2 = a2 / mx;
                float w0v = (q0 > THRV) ? q0 : 0.f;
                float w1v = (q1 > THRV) ? q1 : 0.f;
                float w2v = (q2 > THRV) ? q2 : 0.f;
                for (int u = u0; u < TT; u += 2) {
                    out[rowbase + (size_t)u * CC + lane]      = w0v;
                    out[rowbase + (size_t)u * CC + 32 + lane] = w1v;
                    out[rowbase + (size_t)u * CC + 64 + lane] = w2v;
                }
            }
        }
        // lens: frozen pattern's char-52 hit (if any) recorded at tex-2 / tex-1.
    }

    if (w >= 8 && lane == 0) lens[b0 + (w - 8)] = (float)len;
}

extern "C" void kernel_launch(void* const* d_in, const int* in_sizes, int n_in,
                              void* d_out, int out_size, void* d_ws, size_t ws_size,
                              hipStream_t stream)
{
    const float* img = (const float*)d_in[0];
    const float* l1w = (const float*)d_in[1];
    const float* l1b = (const float*)d_in[2];
    const float* wih = (const float*)d_in[3];
    const float* whh = (const float*)d_in[4];
    const float* bih = (const float*)d_in[5];
    const float* bhh = (const float*)d_in[6];
    const float* l2w = (const float*)d_in[7];
    const float* l2b = (const float*)d_in[8];

    float* out  = (float*)d_out;
    float* lens = out + (size_t)2048 * TT * CC;

    // no memset: the kernel writes every title element exactly once
    // (full-row coalesced stores with explicit zeros) and all lens entries.
    gru_title<<<dim3(2048 / NB), dim3(1024), 0, stream>>>(
        img, l1w, l1b, wih, whh, bih, bhh, l2w, l2b, out, lens);
}